// Round 5
// baseline (209.144 us; speedup 1.0000x reference)
//
#include <hip/hip_runtime.h>
#include <hip/hip_bf16.h>

typedef __attribute__((ext_vector_type(8))) short short8;
typedef __attribute__((ext_vector_type(4))) float floatx4;

__device__ __forceinline__ ushort f2bf(float f) {
    union { __hip_bfloat16 h; ushort u; } cv;
    cv.h = __float2bfloat16(f);
    return cv.u;
}
__device__ __forceinline__ float bf2f(ushort u) {
    union { ushort u; __hip_bfloat16 h; } cv;
    cv.u = u;
    return __bfloat162float(cv.h);
}
// truncating f32->bf16 (RTZ): 1 shr. Used for P only (bias cancels in softmax ratio).
__device__ __forceinline__ ushort f2bf_rtz(float f) {
    union { float f; unsigned u; } cv;
    cv.f = f;
    return (ushort)(cv.u >> 16);
}

typedef __attribute__((address_space(1))) void* gas1_t;
typedef __attribute__((address_space(3))) void* las3_t;
// async global->LDS, 16B per lane. LDS dest = wave-uniform base + lane*16.
__device__ __forceinline__ void cp16(const ushort* g, ushort* l) {
    __builtin_amdgcn_global_load_lds((gas1_t)(unsigned long long)g,
                                     (las3_t)(unsigned long long)l, 16, 0, 0);
}

// ---------------------------------------------------------------------------
// Kernel 1: cast + transpose weights fp32[R][C] -> bf16[C][R]
// ---------------------------------------------------------------------------
__global__ __launch_bounds__(256) void transpose_cast(const float* __restrict__ in,
                                                      ushort* __restrict__ out,
                                                      int R, int C) {
    __shared__ float tile[32][33];
    int c0 = blockIdx.x * 32, r0 = blockIdx.y * 32;
    int tx = threadIdx.x, ty = threadIdx.y;
    for (int j = 0; j < 32; j += 8)
        tile[ty + j][tx] = in[(size_t)(r0 + ty + j) * C + c0 + tx];
    __syncthreads();
    for (int j = 0; j < 32; j += 8)
        out[(size_t)(c0 + ty + j) * R + r0 + tx] = f2bf(tile[tx][ty + j]);
}

// ---------------------------------------------------------------------------
// Kernel 2: LayerNorm (fp32) -> bf16. One block per row of 1024.
// ---------------------------------------------------------------------------
__global__ __launch_bounds__(256) void ln_kernel(const float* __restrict__ x,
                                                 const float* __restrict__ lw,
                                                 const float* __restrict__ lb,
                                                 ushort* __restrict__ xn) {
    int row = blockIdx.x;
    int tid = threadIdx.x;
    const float4* xr = (const float4*)(x + (size_t)row * 1024);
    float4 v = xr[tid];
    float s = v.x + v.y + v.z + v.w;
    float sq = v.x * v.x + v.y * v.y + v.z * v.z + v.w * v.w;
    for (int off = 32; off; off >>= 1) {
        s += __shfl_xor(s, off);
        sq += __shfl_xor(sq, off);
    }
    __shared__ float ls[4], lq[4];
    int wave = tid >> 6, lane = tid & 63;
    if (lane == 0) { ls[wave] = s; lq[wave] = sq; }
    __syncthreads();
    s = ls[0] + ls[1] + ls[2] + ls[3];
    sq = lq[0] + lq[1] + lq[2] + lq[3];
    float mu = s * (1.0f / 1024.0f);
    float var = sq * (1.0f / 1024.0f) - mu * mu;
    float rs = rsqrtf(var + 1e-5f);
    const float4* wr = (const float4*)lw;
    const float4* br = (const float4*)lb;
    float4 wv = wr[tid], bv = br[tid];
    ushort4 o;
    o.x = f2bf((v.x - mu) * rs * wv.x + bv.x);
    o.y = f2bf((v.y - mu) * rs * wv.y + bv.y);
    o.z = f2bf((v.z - mu) * rs * wv.z + bv.z);
    o.w = f2bf((v.w - mu) * rs * wv.w + bv.w);
    *(ushort4*)&xn[(size_t)row * 1024 + tid * 4] = o;
}

// ---------------------------------------------------------------------------
// Kernel 3: MFMA GEMM with single-barrier double-buffered K-loop:
//   sync -> issue cp16(t+1) into other buffer -> compute tile t.
// C[M][N] = A[M][K] @ Bt[N][K]^T. 128x128 tile, 4 waves, 4x4 16x16x32 MFMA.
// LDS: unpadded BK=32, 16B-chunk XOR swizzle (slot = seg ^ (row&3)).
// ---------------------------------------------------------------------------
template <typename OutT>
__global__ __launch_bounds__(256) void gemm_bt(const ushort* __restrict__ A,
                                               const ushort* __restrict__ Bt,
                                               OutT* __restrict__ C,
                                               int M, int N, int K) {
    __shared__ ushort As[2][128 * 32];
    __shared__ ushort Bs[2][128 * 32];
    const int tid = threadIdx.x;
    const int wave = tid >> 6, lane = tid & 63;
    const int quad = lane >> 4, l15 = lane & 15;
    const int wm = (wave >> 1) * 64, wn = (wave & 1) * 64;
    const int bm = blockIdx.y * 128, bn = blockIdx.x * 128;

    const int s0 = tid, s1 = tid + 256;
    const int row0 = s0 >> 2, src0 = (s0 & 3) ^ (row0 & 3);
    const int row1 = s1 >> 2, src1 = (s1 & 3) ^ (row1 & 3);

    floatx4 acc[4][4];
    floatx4 z4 = {0.f, 0.f, 0.f, 0.f};
    for (int mi = 0; mi < 4; mi++)
        for (int ni = 0; ni < 4; ni++) acc[mi][ni] = z4;

    const ushort* Ap0 = A + (size_t)(bm + row0) * K + src0 * 8;
    const ushort* Ap1 = A + (size_t)(bm + row1) * K + src1 * 8;
    const ushort* Bp0 = Bt + (size_t)(bn + row0) * K + src0 * 8;
    const ushort* Bp1 = Bt + (size_t)(bn + row1) * K + src1 * 8;

    const int T = K >> 5;
    cp16(Ap0, &As[0][wave * 512]);
    cp16(Ap1, &As[0][2048 + wave * 512]);
    cp16(Bp0, &Bs[0][wave * 512]);
    cp16(Bp1, &Bs[0][2048 + wave * 512]);

    for (int t = 0; t < T; t++) {
        __syncthreads();               // drains cp16(t) -> tile t published
        if (t + 1 < T) {               // prefetch t+1 during compute of t
            const int nb = (t + 1) & 1;
            const int k0n = (t + 1) << 5;
            cp16(Ap0 + k0n, &As[nb][wave * 512]);
            cp16(Ap1 + k0n, &As[nb][2048 + wave * 512]);
            cp16(Bp0 + k0n, &Bs[nb][wave * 512]);
            cp16(Bp1 + k0n, &Bs[nb][2048 + wave * 512]);
        }
        const ushort* Ab = As[t & 1];
        const ushort* Bb = Bs[t & 1];
        short8 af[4], bfr[4];
        for (int mi = 0; mi < 4; mi++) {
            int ra = wm + mi * 16 + l15;
            af[mi] = *(const short8*)&Ab[ra * 32 + ((quad ^ (ra & 3)) << 3)];
        }
        for (int ni = 0; ni < 4; ni++) {
            int rb = wn + ni * 16 + l15;
            bfr[ni] = *(const short8*)&Bb[rb * 32 + ((quad ^ (rb & 3)) << 3)];
        }
        for (int mi = 0; mi < 4; mi++)
            for (int ni = 0; ni < 4; ni++)
                acc[mi][ni] = __builtin_amdgcn_mfma_f32_16x16x32_bf16(
                    af[mi], bfr[ni], acc[mi][ni], 0, 0, 0);
    }
    for (int mi = 0; mi < 4; mi++) {
        for (int ni = 0; ni < 4; ni++) {
            for (int r = 0; r < 4; r++) {
                int row = bm + wm + mi * 16 + quad * 4 + r;
                int col = bn + wn + ni * 16 + l15;
                float val = acc[mi][ni][r];
                if constexpr (sizeof(OutT) == 2)
                    ((ushort*)C)[(size_t)row * N + col] = f2bf(val);
                else
                    ((float*)C)[(size_t)row * N + col] = val;
            }
        }
    }
}

// ---------------------------------------------------------------------------
// Kernel 4: prep — emits flash-friendly CONTIGUOUS-TILE layouts:
//   Kt[bh][n][64]        raw K rows, packed (64-row tile = 8 KB contiguous)
//   Vb[bh][nb][d][64]    V transposed AND blocked per 64-tile (8 KB contiguous)
//   qn/kn[bh][n]         1/||row|| (fp32), folded into flash softmax
// ---------------------------------------------------------------------------
__global__ __launch_bounds__(256) void prep(const ushort* __restrict__ qkv,
                                            ushort* __restrict__ Kt,
                                            ushort* __restrict__ Vb,
                                            float* __restrict__ qn,
                                            float* __restrict__ kn) {
    const int nb = blockIdx.x;   // n-tile of 64
    const int h = blockIdx.y;
    const int b = blockIdx.z;
    const int bh = b * 16 + h;
    const int tid = threadIdx.x, wave = tid >> 6, lane = tid & 63;
    __shared__ ushort vt[64][72];  // [d][n_loc]

    union S8 { short8 v; ushort u[8]; };
    for (int i = 0; i < 2; i++) {
        int c = tid + i * 256;
        int nl = c >> 3, sg = c & 7;
        S8 vv;
        vv.v = *(const short8*)&qkv[(size_t)(b * 2048 + nb * 64 + nl) * 3072 + 2048 + h * 64 + sg * 8];
        for (int j = 0; j < 8; j++) vt[sg * 8 + j][nl] = vv.u[j];
    }
    __syncthreads();
    for (int i = 0; i < 2; i++) {
        int c = tid + i * 256;
        int d = c >> 3, sg = c & 7;
        *(short8*)&Vb[((size_t)bh * 32 + nb) * 4096 + d * 64 + sg * 8] =
            *(const short8*)&vt[d][sg * 8];
    }

    for (int j = 0; j < 16; j++) {
        int nl = wave * 16 + j;
        size_t rowb = (size_t)(b * 2048 + nb * 64 + nl) * 3072 + h * 64;
        float qv = bf2f(qkv[rowb + lane]);
        float ss = qv * qv;
        for (int off = 32; off; off >>= 1) ss += __shfl_xor(ss, off);
        if (lane == 0) qn[(size_t)bh * 2048 + nb * 64 + nl] = 1.0f / fmaxf(sqrtf(ss), 1e-12f);
        ushort kraw = qkv[rowb + 1024 + lane];
        float kv = bf2f(kraw);
        ss = kv * kv;
        for (int off = 32; off; off >>= 1) ss += __shfl_xor(ss, off);
        if (lane == 0) kn[(size_t)bh * 2048 + nb * 64 + nl] = 1.0f / fmaxf(sqrtf(ss), 1e-12f);
        Kt[((size_t)bh * 2048 + nb * 64 + nl) * 64 + lane] = kraw;  // 128B/wave, coalesced
    }
}

// ---------------------------------------------------------------------------
// Kernel 5: causal flash attention v5 — DENSE K/V staging.
// K/V tiles are 8 KB contiguous (Kt packed, Vb blocked) -> each cp16 wave
// reads 1 KB contiguous. One barrier per k-tile, async dbuf:
//   sync -> issue cp16(t+1) -> compute(t).
// Norms folded: e = exp2((s*kn_j)*(C*qn_i) - C), C = 8*log2(e). P stored RTZ.
// ---------------------------------------------------------------------------
#define LOG2E8 11.541560327111707f   // 8 * log2(e)

__global__ __launch_bounds__(256) void flash_attn(const ushort* __restrict__ qkv,
                                                  const float* __restrict__ qn,
                                                  const float* __restrict__ kn,
                                                  const ushort* __restrict__ Kt,
                                                  const ushort* __restrict__ Vb,
                                                  ushort* __restrict__ O) {
    const int pairi = blockIdx.x;  // 0..15
    const int h = blockIdx.y;
    const int b = blockIdx.z;
    const int bh = b * 16 + h;
    const int tid = threadIdx.x;
    const int wave = tid >> 6, lane = tid & 63;
    const int quad = lane >> 4, l15 = lane & 15;

    __shared__ ushort Ks[2][64 * 64];
    __shared__ ushort Vs[2][64 * 64];
    __shared__ ushort Ps[4][16 * 72];

    // staging: 512 chunks/tile, 2 per thread. chunk ch: row=ch>>3, slot=ch&7,
    // content = tile seg (slot ^ (row&7))  [8-slot XOR swizzle, within 8KB tile]
    const int ch0 = tid, ch1 = tid + 256;
    const int r0 = ch0 >> 3, sg0 = (ch0 & 7) ^ (r0 & 7);
    const int r1 = ch1 >> 3, sg1 = (ch1 & 7) ^ (r1 & 7);

    const ushort* Kp0 = Kt + ((size_t)bh * 2048 + r0) * 64 + sg0 * 8;
    const ushort* Kp1 = Kt + ((size_t)bh * 2048 + r1) * 64 + sg1 * 8;
    const ushort* Vp0 = Vb + (size_t)bh * 131072 + r0 * 64 + sg0 * 8;
    const ushort* Vp1 = Vb + (size_t)bh * 131072 + r1 * 64 + sg1 * 8;

    const float* knb = kn + (size_t)bh * 2048;
    floatx4 z4 = {0.f, 0.f, 0.f, 0.f};

    for (int pass = 0; pass < 2; pass++) {
        const int st = pass ? (31 - pairi) : pairi;
        const int q0 = st * 64;

        // Q fragments direct from global (raw, un-normalized)
        const ushort* Qp = qkv + (size_t)(b * 2048 + q0 + wave * 16 + l15) * 3072 + h * 64;
        short8 qf0 = *(const short8*)(Qp + quad * 8);
        short8 qf1 = *(const short8*)(Qp + 32 + quad * 8);
        float a_r[4];
        for (int r = 0; r < 4; r++)
            a_r[r] = LOG2E8 * qn[(size_t)bh * 2048 + q0 + wave * 16 + quad * 4 + r];

        float rs_acc[4] = {0.f, 0.f, 0.f, 0.f};
        floatx4 o_acc[4];
        for (int ni = 0; ni < 4; ni++) o_acc[ni] = z4;

        __syncthreads();  // prior pass's LDS readers done before re-staging buf0
        cp16(Kp0, &Ks[0][wave * 512]);           // pre-issue tile 0
        cp16(Kp1, &Ks[0][2048 + wave * 512]);
        cp16(Vp0, &Vs[0][wave * 512]);
        cp16(Vp1, &Vs[0][2048 + wave * 512]);

        for (int kt = 0; kt <= st; kt++) {
            const int kv0 = kt * 64;
            __syncthreads();                     // drains cp16(kt) -> published
            if (kt < st) {                       // prefetch kt+1 during compute
                const int nb2 = (kt + 1) & 1;
                const size_t to = (size_t)(kt + 1) * 4096;   // 8KB tile stride
                cp16(Kp0 + to, &Ks[nb2][wave * 512]);
                cp16(Kp1 + to, &Ks[nb2][2048 + wave * 512]);
                cp16(Vp0 + to, &Vs[nb2][wave * 512]);
                cp16(Vp1 + to, &Vs[nb2][2048 + wave * 512]);
            }
            const ushort* Kb = Ks[kt & 1];
            const ushort* Vb_ = Vs[kt & 1];

            // S = Q K^T (raw)
            floatx4 s_acc[4];
            for (int ni = 0; ni < 4; ni++) s_acc[ni] = z4;
            for (int ni = 0; ni < 4; ni++) {
                int rb = ni * 16 + l15;
                short8 kf0 = *(const short8*)&Kb[rb * 64 + ((quad ^ (rb & 7)) << 3)];
                short8 kf1 = *(const short8*)&Kb[rb * 64 + (((quad + 4) ^ (rb & 7)) << 3)];
                s_acc[ni] = __builtin_amdgcn_mfma_f32_16x16x32_bf16(qf0, kf0, s_acc[ni], 0, 0, 0);
                s_acc[ni] = __builtin_amdgcn_mfma_f32_16x16x32_bf16(qf1, kf1, s_acc[ni], 0, 0, 0);
            }

            // softmax numerator: e = exp2((s*kn)*(C*qn) - C), fixed max (sim<=8)
            const bool diag = (kt == st);
            for (int ni = 0; ni < 4; ni++) {
                const int col_loc = ni * 16 + l15;
                const float knv = knb[kv0 + col_loc];
                for (int r = 0; r < 4; r++) {
                    float e = __builtin_amdgcn_exp2f(
                        fmaf(s_acc[ni][r] * knv, a_r[r], -LOG2E8));
                    if (diag && col_loc > wave * 16 + quad * 4 + r) e = 0.f;
                    rs_acc[r] += e;
                    Ps[wave][(quad * 4 + r) * 72 + col_loc] = f2bf_rtz(e);
                }
            }

            // P (same-wave LDS roundtrip) -> A-layout, then PV
            short8 pa0 = *(const short8*)&Ps[wave][l15 * 72 + quad * 8];
            short8 pa1 = *(const short8*)&Ps[wave][l15 * 72 + 32 + quad * 8];
            for (int ni = 0; ni < 4; ni++) {
                int rv = ni * 16 + l15;
                short8 v0 = *(const short8*)&Vb_[rv * 64 + ((quad ^ (rv & 7)) << 3)];
                short8 v1 = *(const short8*)&Vb_[rv * 64 + (((quad + 4) ^ (rv & 7)) << 3)];
                o_acc[ni] = __builtin_amdgcn_mfma_f32_16x16x32_bf16(pa0, v0, o_acc[ni], 0, 0, 0);
                o_acc[ni] = __builtin_amdgcn_mfma_f32_16x16x32_bf16(pa1, v1, o_acc[ni], 0, 0, 0);
            }
        }

        // epilogue: deferred row-sum reduce, then O/l -> [b, n, h*64+d]
        for (int r = 0; r < 4; r++) {
            float rs = rs_acc[r];
            for (int off = 1; off < 16; off <<= 1) rs += __shfl_xor(rs, off);
            float inv = 1.0f / rs;
            int grow = q0 + wave * 16 + quad * 4 + r;
            size_t rowbase = ((size_t)b * 2048 + grow) * 1024 + h * 64;
            for (int ni = 0; ni < 4; ni++)
                O[rowbase + ni * 16 + l15] = f2bf(o_acc[ni][r] * inv);
        }
    }
}

// ---------------------------------------------------------------------------
extern "C" void kernel_launch(void* const* d_in, const int* in_sizes, int n_in,
                              void* d_out, int out_size, void* d_ws, size_t ws_size,
                              hipStream_t stream) {
    const float* x = (const float*)d_in[0];
    const float* ln_w = (const float*)d_in[1];
    const float* ln_b = (const float*)d_in[2];
    const float* W_qkv = (const float*)d_in[3];
    const float* W_out = (const float*)d_in[4];

    char* w = (char*)d_ws;
    ushort* xn    = (ushort*)(w);                          // 8 MiB
    ushort* WqkvT = (ushort*)(w + (8ull << 20));           // 6 MiB
    ushort* WoutT = (ushort*)(w + (14ull << 20));          // 2 MiB
    ushort* qkv   = (ushort*)(w + (16ull << 20));          // 24 MiB
    ushort* Vb    = (ushort*)(w + (40ull << 20));          // 8 MiB (blocked V)
    float*  qn    = (float*)(w + (48ull << 20));           // 0.25 MiB
    float*  kn    = (float*)(w + (49ull << 20));           // 0.25 MiB
    ushort* obuf  = (ushort*)(w + (50ull << 20));          // 8 MiB
    ushort* Kt    = (ushort*)(w + (58ull << 20));          // 8 MiB -> 66 MiB total

    transpose_cast<<<dim3(96, 32), dim3(32, 8), 0, stream>>>(W_qkv, WqkvT, 1024, 3072);
    transpose_cast<<<dim3(32, 32), dim3(32, 8), 0, stream>>>(W_out, WoutT, 1024, 1024);
    ln_kernel<<<4096, 256, 0, stream>>>(x, ln_w, ln_b, xn);
    gemm_bt<ushort><<<dim3(24, 32), 256, 0, stream>>>(xn, WqkvT, qkv, 4096, 3072, 1024);
    prep<<<dim3(32, 16, 2), 256, 0, stream>>>(qkv, Kt, Vb, qn, kn);
    flash_attn<<<dim3(16, 16, 2), 256, 0, stream>>>(qkv, qn, kn, Kt, Vb, obuf);
    gemm_bt<float><<<dim3(8, 32), 256, 0, stream>>>(obuf, WoutT, (float*)d_out, 4096, 1024, 1024);
}

// Round 6
// 196.337 us; speedup vs baseline: 1.0652x; 1.0652x over previous
//
#include <hip/hip_runtime.h>
#include <hip/hip_bf16.h>

typedef __attribute__((ext_vector_type(8))) short short8;
typedef __attribute__((ext_vector_type(4))) float floatx4;

__device__ __forceinline__ ushort f2bf(float f) {
    union { __hip_bfloat16 h; ushort u; } cv;
    cv.h = __float2bfloat16(f);
    return cv.u;
}
__device__ __forceinline__ float bf2f(ushort u) {
    union { ushort u; __hip_bfloat16 h; } cv;
    cv.u = u;
    return __bfloat162float(cv.h);
}
// truncating f32->bf16 (RTZ): 1 shr. Used for P only (bias cancels in softmax ratio).
__device__ __forceinline__ ushort f2bf_rtz(float f) {
    union { float f; unsigned u; } cv;
    cv.f = f;
    return (ushort)(cv.u >> 16);
}

typedef __attribute__((address_space(1))) void* gas1_t;
typedef __attribute__((address_space(3))) void* las3_t;
// async global->LDS, 16B per lane. LDS dest = wave-uniform base + lane*16.
__device__ __forceinline__ void cp16(const ushort* g, ushort* l) {
    __builtin_amdgcn_global_load_lds((gas1_t)(unsigned long long)g,
                                     (las3_t)(unsigned long long)l, 16, 0, 0);
}

// ---------------------------------------------------------------------------
// Kernel 1: cast + transpose weights fp32[R][C] -> bf16[C][R]
// ---------------------------------------------------------------------------
__global__ __launch_bounds__(256) void transpose_cast(const float* __restrict__ in,
                                                      ushort* __restrict__ out,
                                                      int R, int C) {
    __shared__ float tile[32][33];
    int c0 = blockIdx.x * 32, r0 = blockIdx.y * 32;
    int tx = threadIdx.x, ty = threadIdx.y;
    for (int j = 0; j < 32; j += 8)
        tile[ty + j][tx] = in[(size_t)(r0 + ty + j) * C + c0 + tx];
    __syncthreads();
    for (int j = 0; j < 32; j += 8)
        out[(size_t)(c0 + ty + j) * R + r0 + tx] = f2bf(tile[tx][ty + j]);
}

// ---------------------------------------------------------------------------
// Kernel 2: LayerNorm (fp32) -> bf16. One block per row of 1024.
// ---------------------------------------------------------------------------
__global__ __launch_bounds__(256) void ln_kernel(const float* __restrict__ x,
                                                 const float* __restrict__ lw,
                                                 const float* __restrict__ lb,
                                                 ushort* __restrict__ xn) {
    int row = blockIdx.x;
    int tid = threadIdx.x;
    const float4* xr = (const float4*)(x + (size_t)row * 1024);
    float4 v = xr[tid];
    float s = v.x + v.y + v.z + v.w;
    float sq = v.x * v.x + v.y * v.y + v.z * v.z + v.w * v.w;
    for (int off = 32; off; off >>= 1) {
        s += __shfl_xor(s, off);
        sq += __shfl_xor(sq, off);
    }
    __shared__ float ls[4], lq[4];
    int wave = tid >> 6, lane = tid & 63;
    if (lane == 0) { ls[wave] = s; lq[wave] = sq; }
    __syncthreads();
    s = ls[0] + ls[1] + ls[2] + ls[3];
    sq = lq[0] + lq[1] + lq[2] + lq[3];
    float mu = s * (1.0f / 1024.0f);
    float var = sq * (1.0f / 1024.0f) - mu * mu;
    float rs = rsqrtf(var + 1e-5f);
    const float4* wr = (const float4*)lw;
    const float4* br = (const float4*)lb;
    float4 wv = wr[tid], bv = br[tid];
    ushort4 o;
    o.x = f2bf((v.x - mu) * rs * wv.x + bv.x);
    o.y = f2bf((v.y - mu) * rs * wv.y + bv.y);
    o.z = f2bf((v.z - mu) * rs * wv.z + bv.z);
    o.w = f2bf((v.w - mu) * rs * wv.w + bv.w);
    *(ushort4*)&xn[(size_t)row * 1024 + tid * 4] = o;
}

// ---------------------------------------------------------------------------
// Kernel 3: MFMA GEMM with single-barrier double-buffered K-loop:
//   sync -> issue cp16(t+1) into other buffer -> compute tile t.
// C[M][N] = A[M][K] @ Bt[N][K]^T. 128x128 tile, 4 waves, 4x4 16x16x32 MFMA.
// LDS: unpadded BK=32, 16B-chunk XOR swizzle (slot = seg ^ (row&3)).
// ---------------------------------------------------------------------------
template <typename OutT>
__global__ __launch_bounds__(256) void gemm_bt(const ushort* __restrict__ A,
                                               const ushort* __restrict__ Bt,
                                               OutT* __restrict__ C,
                                               int M, int N, int K) {
    __shared__ ushort As[2][128 * 32];
    __shared__ ushort Bs[2][128 * 32];
    const int tid = threadIdx.x;
    const int wave = tid >> 6, lane = tid & 63;
    const int quad = lane >> 4, l15 = lane & 15;
    const int wm = (wave >> 1) * 64, wn = (wave & 1) * 64;
    const int bm = blockIdx.y * 128, bn = blockIdx.x * 128;

    const int s0 = tid, s1 = tid + 256;
    const int row0 = s0 >> 2, src0 = (s0 & 3) ^ (row0 & 3);
    const int row1 = s1 >> 2, src1 = (s1 & 3) ^ (row1 & 3);

    floatx4 acc[4][4];
    floatx4 z4 = {0.f, 0.f, 0.f, 0.f};
    for (int mi = 0; mi < 4; mi++)
        for (int ni = 0; ni < 4; ni++) acc[mi][ni] = z4;

    const ushort* Ap0 = A + (size_t)(bm + row0) * K + src0 * 8;
    const ushort* Ap1 = A + (size_t)(bm + row1) * K + src1 * 8;
    const ushort* Bp0 = Bt + (size_t)(bn + row0) * K + src0 * 8;
    const ushort* Bp1 = Bt + (size_t)(bn + row1) * K + src1 * 8;

    const int T = K >> 5;
    cp16(Ap0, &As[0][wave * 512]);
    cp16(Ap1, &As[0][2048 + wave * 512]);
    cp16(Bp0, &Bs[0][wave * 512]);
    cp16(Bp1, &Bs[0][2048 + wave * 512]);

    for (int t = 0; t < T; t++) {
        __syncthreads();               // drains cp16(t) -> tile t published
        if (t + 1 < T) {               // prefetch t+1 during compute of t
            const int nb = (t + 1) & 1;
            const int k0n = (t + 1) << 5;
            cp16(Ap0 + k0n, &As[nb][wave * 512]);
            cp16(Ap1 + k0n, &As[nb][2048 + wave * 512]);
            cp16(Bp0 + k0n, &Bs[nb][wave * 512]);
            cp16(Bp1 + k0n, &Bs[nb][2048 + wave * 512]);
        }
        const ushort* Ab = As[t & 1];
        const ushort* Bb = Bs[t & 1];
        short8 af[4], bfr[4];
        for (int mi = 0; mi < 4; mi++) {
            int ra = wm + mi * 16 + l15;
            af[mi] = *(const short8*)&Ab[ra * 32 + ((quad ^ (ra & 3)) << 3)];
        }
        for (int ni = 0; ni < 4; ni++) {
            int rb = wn + ni * 16 + l15;
            bfr[ni] = *(const short8*)&Bb[rb * 32 + ((quad ^ (rb & 3)) << 3)];
        }
        for (int mi = 0; mi < 4; mi++)
            for (int ni = 0; ni < 4; ni++)
                acc[mi][ni] = __builtin_amdgcn_mfma_f32_16x16x32_bf16(
                    af[mi], bfr[ni], acc[mi][ni], 0, 0, 0);
    }
    for (int mi = 0; mi < 4; mi++) {
        for (int ni = 0; ni < 4; ni++) {
            for (int r = 0; r < 4; r++) {
                int row = bm + wm + mi * 16 + quad * 4 + r;
                int col = bn + wn + ni * 16 + l15;
                float val = acc[mi][ni][r];
                if constexpr (sizeof(OutT) == 2)
                    ((ushort*)C)[(size_t)row * N + col] = f2bf(val);
                else
                    ((float*)C)[(size_t)row * N + col] = val;
            }
        }
    }
}

// ---------------------------------------------------------------------------
// Kernel 4: prep — emits flash-friendly layouts, NORMALIZED q/k:
//   Qt[bh][n][64]        q̂ = q/||q||, packed bf16
//   Kt[bh][n][64]        k̂ = k/||k||, packed bf16 (64-row tile = 8 KB contig)
//   Vb[bh][nb][d][64]    V transposed AND blocked per 64-tile (8 KB contig)
// ---------------------------------------------------------------------------
__global__ __launch_bounds__(256) void prep(const ushort* __restrict__ qkv,
                                            ushort* __restrict__ Qt,
                                            ushort* __restrict__ Kt,
                                            ushort* __restrict__ Vb) {
    const int nb = blockIdx.x;   // n-tile of 64
    const int h = blockIdx.y;
    const int b = blockIdx.z;
    const int bh = b * 16 + h;
    const int tid = threadIdx.x, wave = tid >> 6, lane = tid & 63;
    __shared__ ushort vt[64][72];  // [d][n_loc]

    union S8 { short8 v; ushort u[8]; };
    for (int i = 0; i < 2; i++) {
        int c = tid + i * 256;
        int nl = c >> 3, sg = c & 7;
        S8 vv;
        vv.v = *(const short8*)&qkv[(size_t)(b * 2048 + nb * 64 + nl) * 3072 + 2048 + h * 64 + sg * 8];
        for (int j = 0; j < 8; j++) vt[sg * 8 + j][nl] = vv.u[j];
    }
    __syncthreads();
    for (int i = 0; i < 2; i++) {
        int c = tid + i * 256;
        int d = c >> 3, sg = c & 7;
        *(short8*)&Vb[((size_t)bh * 32 + nb) * 4096 + d * 64 + sg * 8] =
            *(const short8*)&vt[d][sg * 8];
    }

    for (int j = 0; j < 16; j++) {
        int nl = wave * 16 + j;
        size_t rowb = (size_t)(b * 2048 + nb * 64 + nl) * 3072 + h * 64;
        size_t orow = ((size_t)bh * 2048 + nb * 64 + nl) * 64;

        float qv = bf2f(qkv[rowb + lane]);
        float ss = qv * qv;
        for (int off = 32; off; off >>= 1) ss += __shfl_xor(ss, off);
        float inv = 1.0f / fmaxf(sqrtf(ss), 1e-12f);
        Qt[orow + lane] = f2bf(qv * inv);

        float kv = bf2f(qkv[rowb + 1024 + lane]);
        ss = kv * kv;
        for (int off = 32; off; off >>= 1) ss += __shfl_xor(ss, off);
        inv = 1.0f / fmaxf(sqrtf(ss), 1e-12f);
        Kt[orow + lane] = f2bf(kv * inv);
    }
}

// ---------------------------------------------------------------------------
// Kernel 5: causal flash attention v6 — XCD-LOCAL K/V + prenormalized q,k.
// 1-D grid 512, decode: xcd = id&7, slot = id>>3, bh = xcd*4 + slot/16,
// pairi = slot&15  -> all 16 blocks sharing a bh land on ONE XCD's L2
// (4 bh/XCD x 1 MB K/V = 4 MB = L2 size). Staging becomes L2-hit and the
// single-barrier dbuf hides it under compute.
// Softmax: e = exp2(s*C - C), C = 8*log2(e), s = q̂·k̂ from MFMA. P stored RTZ.
// ---------------------------------------------------------------------------
#define LOG2E8 11.541560327111707f   // 8 * log2(e)

__global__ __launch_bounds__(256) void flash_attn(const ushort* __restrict__ Qt,
                                                  const ushort* __restrict__ Kt,
                                                  const ushort* __restrict__ Vb,
                                                  ushort* __restrict__ O) {
    const int id = blockIdx.x;
    const int xcd = id & 7, slot = id >> 3;
    const int bh = xcd * 4 + (slot >> 4);
    const int pairi = slot & 15;
    const int b = bh >> 4, h = bh & 15;
    const int tid = threadIdx.x;
    const int wave = tid >> 6, lane = tid & 63;
    const int quad = lane >> 4, l15 = lane & 15;

    __shared__ ushort Ks[2][64 * 64];
    __shared__ ushort Vs[2][64 * 64];
    __shared__ ushort Ps[4][16 * 72];

    // staging: 512 chunks/tile, 2 per thread. chunk ch: row=ch>>3, slot=ch&7,
    // content = tile seg (slot ^ (row&7))  [8-slot XOR swizzle, within 8KB tile]
    const int ch0 = tid, ch1 = tid + 256;
    const int r0 = ch0 >> 3, sg0 = (ch0 & 7) ^ (r0 & 7);
    const int r1 = ch1 >> 3, sg1 = (ch1 & 7) ^ (r1 & 7);

    const ushort* Kp0 = Kt + ((size_t)bh * 2048 + r0) * 64 + sg0 * 8;
    const ushort* Kp1 = Kt + ((size_t)bh * 2048 + r1) * 64 + sg1 * 8;
    const ushort* Vp0 = Vb + (size_t)bh * 131072 + r0 * 64 + sg0 * 8;
    const ushort* Vp1 = Vb + (size_t)bh * 131072 + r1 * 64 + sg1 * 8;

    floatx4 z4 = {0.f, 0.f, 0.f, 0.f};

    for (int pass = 0; pass < 2; pass++) {
        const int st = pass ? (31 - pairi) : pairi;
        const int q0 = st * 64;

        // Q fragments direct from global (prenormalized, packed rows)
        const ushort* Qp = Qt + ((size_t)bh * 2048 + q0 + wave * 16 + l15) * 64;
        short8 qf0 = *(const short8*)(Qp + quad * 8);
        short8 qf1 = *(const short8*)(Qp + 32 + quad * 8);

        float rs_acc[4] = {0.f, 0.f, 0.f, 0.f};
        floatx4 o_acc[4];
        for (int ni = 0; ni < 4; ni++) o_acc[ni] = z4;

        __syncthreads();  // prior pass's LDS readers done before re-staging buf0
        cp16(Kp0, &Ks[0][wave * 512]);           // pre-issue tile 0
        cp16(Kp1, &Ks[0][2048 + wave * 512]);
        cp16(Vp0, &Vs[0][wave * 512]);
        cp16(Vp1, &Vs[0][2048 + wave * 512]);

        for (int kt = 0; kt <= st; kt++) {
            __syncthreads();                     // drains cp16(kt) -> published
            if (kt < st) {                       // prefetch kt+1 during compute
                const int nb2 = (kt + 1) & 1;
                const size_t to = (size_t)(kt + 1) * 4096;   // 8KB tile stride
                cp16(Kp0 + to, &Ks[nb2][wave * 512]);
                cp16(Kp1 + to, &Ks[nb2][2048 + wave * 512]);
                cp16(Vp0 + to, &Vs[nb2][wave * 512]);
                cp16(Vp1 + to, &Vs[nb2][2048 + wave * 512]);
            }
            const ushort* Kb = Ks[kt & 1];
            const ushort* Vb_ = Vs[kt & 1];

            // S = Q̂ K̂^T
            floatx4 s_acc[4];
            for (int ni = 0; ni < 4; ni++) s_acc[ni] = z4;
            for (int ni = 0; ni < 4; ni++) {
                int rb = ni * 16 + l15;
                short8 kf0 = *(const short8*)&Kb[rb * 64 + ((quad ^ (rb & 7)) << 3)];
                short8 kf1 = *(const short8*)&Kb[rb * 64 + (((quad + 4) ^ (rb & 7)) << 3)];
                s_acc[ni] = __builtin_amdgcn_mfma_f32_16x16x32_bf16(qf0, kf0, s_acc[ni], 0, 0, 0);
                s_acc[ni] = __builtin_amdgcn_mfma_f32_16x16x32_bf16(qf1, kf1, s_acc[ni], 0, 0, 0);
            }

            // softmax numerator: e = exp2(s*C - C), fixed max (s<=1)
            const bool diag = (kt == st);
            for (int ni = 0; ni < 4; ni++) {
                const int col_loc = ni * 16 + l15;
                for (int r = 0; r < 4; r++) {
                    float e = __builtin_amdgcn_exp2f(
                        fmaf(s_acc[ni][r], LOG2E8, -LOG2E8));
                    if (diag && col_loc > wave * 16 + quad * 4 + r) e = 0.f;
                    rs_acc[r] += e;
                    Ps[wave][(quad * 4 + r) * 72 + col_loc] = f2bf_rtz(e);
                }
            }

            // P (same-wave LDS roundtrip) -> A-layout, then PV
            short8 pa0 = *(const short8*)&Ps[wave][l15 * 72 + quad * 8];
            short8 pa1 = *(const short8*)&Ps[wave][l15 * 72 + 32 + quad * 8];
            for (int ni = 0; ni < 4; ni++) {
                int rv = ni * 16 + l15;
                short8 v0 = *(const short8*)&Vb_[rv * 64 + ((quad ^ (rv & 7)) << 3)];
                short8 v1 = *(const short8*)&Vb_[rv * 64 + (((quad + 4) ^ (rv & 7)) << 3)];
                o_acc[ni] = __builtin_amdgcn_mfma_f32_16x16x32_bf16(pa0, v0, o_acc[ni], 0, 0, 0);
                o_acc[ni] = __builtin_amdgcn_mfma_f32_16x16x32_bf16(pa1, v1, o_acc[ni], 0, 0, 0);
            }
        }

        // epilogue: deferred row-sum reduce, then O/l -> [b, n, h*64+d]
        for (int r = 0; r < 4; r++) {
            float rs = rs_acc[r];
            for (int off = 1; off < 16; off <<= 1) rs += __shfl_xor(rs, off);
            float inv = 1.0f / rs;
            int grow = q0 + wave * 16 + quad * 4 + r;
            size_t rowbase = ((size_t)b * 2048 + grow) * 1024 + h * 64;
            for (int ni = 0; ni < 4; ni++)
                O[rowbase + ni * 16 + l15] = f2bf(o_acc[ni][r] * inv);
        }
    }
}

// ---------------------------------------------------------------------------
extern "C" void kernel_launch(void* const* d_in, const int* in_sizes, int n_in,
                              void* d_out, int out_size, void* d_ws, size_t ws_size,
                              hipStream_t stream) {
    const float* x = (const float*)d_in[0];
    const float* ln_w = (const float*)d_in[1];
    const float* ln_b = (const float*)d_in[2];
    const float* W_qkv = (const float*)d_in[3];
    const float* W_out = (const float*)d_in[4];

    char* w = (char*)d_ws;
    ushort* xn    = (ushort*)(w);                          // 8 MiB
    ushort* WqkvT = (ushort*)(w + (8ull << 20));           // 6 MiB
    ushort* WoutT = (ushort*)(w + (14ull << 20));          // 2 MiB
    ushort* qkv   = (ushort*)(w + (16ull << 20));          // 24 MiB
    ushort* Vb    = (ushort*)(w + (40ull << 20));          // 8 MiB (blocked V)
    ushort* Qt    = (ushort*)(w + (48ull << 20));          // 8 MiB (normalized)
    ushort* obuf  = (ushort*)(w + (56ull << 20));          // 8 MiB
    ushort* Kt    = (ushort*)(w + (64ull << 20));          // 8 MiB -> 72 MiB total

    transpose_cast<<<dim3(96, 32), dim3(32, 8), 0, stream>>>(W_qkv, WqkvT, 1024, 3072);
    transpose_cast<<<dim3(32, 32), dim3(32, 8), 0, stream>>>(W_out, WoutT, 1024, 1024);
    ln_kernel<<<4096, 256, 0, stream>>>(x, ln_w, ln_b, xn);
    gemm_bt<ushort><<<dim3(24, 32), 256, 0, stream>>>(xn, WqkvT, qkv, 4096, 3072, 1024);
    prep<<<dim3(32, 16, 2), 256, 0, stream>>>(qkv, Qt, Kt, Vb);
    flash_attn<<<512, 256, 0, stream>>>(Qt, Kt, Vb, obuf);
    gemm_bt<float><<<dim3(8, 32), 256, 0, stream>>>(obuf, WoutT, (float*)d_out, 4096, 1024, 1024);
}

// Round 7
// 179.364 us; speedup vs baseline: 1.1660x; 1.0946x over previous
//
#include <hip/hip_runtime.h>
#include <hip/hip_bf16.h>

typedef __attribute__((ext_vector_type(8))) short short8;
typedef __attribute__((ext_vector_type(4))) float floatx4;

__device__ __forceinline__ ushort f2bf(float f) {
    union { __hip_bfloat16 h; ushort u; } cv;
    cv.h = __float2bfloat16(f);
    return cv.u;
}
__device__ __forceinline__ float bf2f(ushort u) {
    union { ushort u; __hip_bfloat16 h; } cv;
    cv.u = u;
    return __bfloat162float(cv.h);
}
// truncating f32->bf16 (RTZ): 1 shr. Used for P only (bias cancels in softmax ratio).
__device__ __forceinline__ ushort f2bf_rtz(float f) {
    union { float f; unsigned u; } cv;
    cv.f = f;
    return (ushort)(cv.u >> 16);
}

typedef __attribute__((address_space(1))) void* gas1_t;
typedef __attribute__((address_space(3))) void* las3_t;
// async global->LDS, 16B per lane. LDS dest = wave-uniform base + lane*16.
__device__ __forceinline__ void cp16(const ushort* g, ushort* l) {
    __builtin_amdgcn_global_load_lds((gas1_t)(unsigned long long)g,
                                     (las3_t)(unsigned long long)l, 16, 0, 0);
}

// ---------------------------------------------------------------------------
// Kernel 1: both weight transposes in one launch. fp32[R][C] -> bf16[C][R].
// grid (128, 32): bx<96 -> W_qkv (1024x3072); bx>=96 -> W_out (1024x1024).
// ---------------------------------------------------------------------------
__global__ __launch_bounds__(256) void transpose_cast2(const float* __restrict__ Wqkv,
                                                       const float* __restrict__ Wout,
                                                       ushort* __restrict__ WqkvT,
                                                       ushort* __restrict__ WoutT) {
    __shared__ float tile[32][33];
    int bx = blockIdx.x, by = blockIdx.y;
    const float* in; ushort* out; int R = 1024, C;
    if (bx < 96) { in = Wqkv; out = WqkvT; C = 3072; }
    else { in = Wout; out = WoutT; C = 1024; bx -= 96; }
    int c0 = bx * 32, r0 = by * 32;
    int tx = threadIdx.x, ty = threadIdx.y;
    for (int j = 0; j < 32; j += 8)
        tile[ty + j][tx] = in[(size_t)(r0 + ty + j) * C + c0 + tx];
    __syncthreads();
    for (int j = 0; j < 32; j += 8)
        out[(size_t)(c0 + ty + j) * R + r0 + tx] = f2bf(tile[tx][ty + j]);
}

// ---------------------------------------------------------------------------
// Kernel 2: LayerNorm (fp32) -> bf16. One block per row of 1024.
// ---------------------------------------------------------------------------
__global__ __launch_bounds__(256) void ln_kernel(const float* __restrict__ x,
                                                 const float* __restrict__ lw,
                                                 const float* __restrict__ lb,
                                                 ushort* __restrict__ xn) {
    int row = blockIdx.x;
    int tid = threadIdx.x;
    const float4* xr = (const float4*)(x + (size_t)row * 1024);
    float4 v = xr[tid];
    float s = v.x + v.y + v.z + v.w;
    float sq = v.x * v.x + v.y * v.y + v.z * v.z + v.w * v.w;
    for (int off = 32; off; off >>= 1) {
        s += __shfl_xor(s, off);
        sq += __shfl_xor(sq, off);
    }
    __shared__ float ls[4], lq[4];
    int wave = tid >> 6, lane = tid & 63;
    if (lane == 0) { ls[wave] = s; lq[wave] = sq; }
    __syncthreads();
    s = ls[0] + ls[1] + ls[2] + ls[3];
    sq = lq[0] + lq[1] + lq[2] + lq[3];
    float mu = s * (1.0f / 1024.0f);
    float var = sq * (1.0f / 1024.0f) - mu * mu;
    float rs = rsqrtf(var + 1e-5f);
    const float4* wr = (const float4*)lw;
    const float4* br = (const float4*)lb;
    float4 wv = wr[tid], bv = br[tid];
    ushort4 o;
    o.x = f2bf((v.x - mu) * rs * wv.x + bv.x);
    o.y = f2bf((v.y - mu) * rs * wv.y + bv.y);
    o.z = f2bf((v.z - mu) * rs * wv.z + bv.z);
    o.w = f2bf((v.w - mu) * rs * wv.w + bv.w);
    *(ushort4*)&xn[(size_t)row * 1024 + tid * 4] = o;
}

// ---------------------------------------------------------------------------
// Kernel 3: FUSED QKV GEMM: qkv = xn @ WqkvT^T, epilogue writes directly to
// flash layouts (raw qkv is never materialized):
//   bn 0..7  (q cols): fp32 row-norm (shfl-reduce over the wave's 64-col head)
//                      -> Qt[bh][n][64] normalized bf16
//   bn 8..15 (k cols): same -> Kt[bh][n][64]
//   bn 16..23 (v cols): per-wave 64x64 LDS transpose -> Vb[bh][nb][d][64]
// Head type is block-uniform (1024-col type boundaries are 128-aligned);
// each wave's 64-col strip is exactly one head (64-aligned).
// K-loop: single-barrier async dbuf (sync -> cp16(t+1) -> compute(t)).
// ---------------------------------------------------------------------------
__global__ __launch_bounds__(256) void gemm_qkv_fused(const ushort* __restrict__ A,
                                                      const ushort* __restrict__ Bt,
                                                      ushort* __restrict__ Qt,
                                                      ushort* __restrict__ Kt,
                                                      ushort* __restrict__ Vb) {
    __shared__ ushort smem[18432];  // K-loop: As=smem[0..8192), Bs=[8192..16384); epilogue: 4x4608
    const int K = 1024, T = 32;
    const int tid = threadIdx.x;
    const int wave = tid >> 6, lane = tid & 63;
    const int quad = lane >> 4, l15 = lane & 15;
    const int wm = (wave >> 1) * 64, wn = (wave & 1) * 64;
    const int bm = blockIdx.y * 128, bn = blockIdx.x;

    const int s0 = tid, s1 = tid + 256;
    const int row0 = s0 >> 2, src0 = (s0 & 3) ^ (row0 & 3);
    const int row1 = s1 >> 2, src1 = (s1 & 3) ^ (row1 & 3);

    floatx4 acc[4][4];
    floatx4 z4 = {0.f, 0.f, 0.f, 0.f};
    for (int mi = 0; mi < 4; mi++)
        for (int ni = 0; ni < 4; ni++) acc[mi][ni] = z4;

    const ushort* Ap0 = A + (size_t)(bm + row0) * K + src0 * 8;
    const ushort* Ap1 = A + (size_t)(bm + row1) * K + src1 * 8;
    const ushort* Bp0 = Bt + (size_t)(bn * 128 + row0) * K + src0 * 8;
    const ushort* Bp1 = Bt + (size_t)(bn * 128 + row1) * K + src1 * 8;

    ushort* As = smem;          // [2][4096]
    ushort* Bs = smem + 8192;   // [2][4096]

    cp16(Ap0, &As[wave * 512]);
    cp16(Ap1, &As[2048 + wave * 512]);
    cp16(Bp0, &Bs[wave * 512]);
    cp16(Bp1, &Bs[2048 + wave * 512]);

    for (int t = 0; t < T; t++) {
        __syncthreads();               // drains cp16(t) -> tile t published
        if (t + 1 < T) {
            const int nb = (t + 1) & 1;
            const int k0n = (t + 1) << 5;
            cp16(Ap0 + k0n, &As[nb * 4096 + wave * 512]);
            cp16(Ap1 + k0n, &As[nb * 4096 + 2048 + wave * 512]);
            cp16(Bp0 + k0n, &Bs[nb * 4096 + wave * 512]);
            cp16(Bp1 + k0n, &Bs[nb * 4096 + 2048 + wave * 512]);
        }
        const ushort* Ab = As + (t & 1) * 4096;
        const ushort* Bb = Bs + (t & 1) * 4096;
        short8 af[4], bfr[4];
        for (int mi = 0; mi < 4; mi++) {
            int ra = wm + mi * 16 + l15;
            af[mi] = *(const short8*)&Ab[ra * 32 + ((quad ^ (ra & 3)) << 3)];
        }
        for (int ni = 0; ni < 4; ni++) {
            int rb = wn + ni * 16 + l15;
            bfr[ni] = *(const short8*)&Bb[rb * 32 + ((quad ^ (rb & 3)) << 3)];
        }
        for (int mi = 0; mi < 4; mi++)
            for (int ni = 0; ni < 4; ni++)
                acc[mi][ni] = __builtin_amdgcn_mfma_f32_16x16x32_bf16(
                    af[mi], bfr[ni], acc[mi][ni], 0, 0, 0);
    }

    // ------------------------- fused epilogue -------------------------
    const int col_base = bn * 128 + wn;          // 64-aligned -> one head/wave
    const int type = col_base >> 10;             // 0=q, 1=k, 2=v (block-uniform)
    const int h = (col_base & 1023) >> 6;
    const int row_base = bm + wm;

    if (type < 2) {
        ushort* dst = (type == 0) ? Qt : Kt;
        for (int mi = 0; mi < 4; mi++) {
            for (int r = 0; r < 4; r++) {
                float ss = 0.f;
                for (int ni = 0; ni < 4; ni++) ss += acc[mi][ni][r] * acc[mi][ni][r];
                for (int off = 1; off < 16; off <<= 1) ss += __shfl_xor(ss, off);
                float inv = rsqrtf(fmaxf(ss, 1e-24f));
                int rg = row_base + mi * 16 + quad * 4 + r;
                int bb = rg >> 11, n = rg & 2047;
                size_t orow = ((size_t)(bb * 16 + h) * 2048 + n) * 64;
                for (int ni = 0; ni < 4; ni++)
                    dst[orow + ni * 16 + l15] = f2bf(acc[mi][ni][r] * inv);
            }
        }
    } else {
        __syncthreads();   // all waves done reading As/Bs -> reuse smem
        ushort* tr = smem + wave * 4608;   // 64 x 72 (144B rows: b128-aligned)
        for (int mi = 0; mi < 4; mi++)
            for (int ni = 0; ni < 4; ni++)
                for (int r = 0; r < 4; r++) {
                    int row_l = mi * 16 + quad * 4 + r;   // n_loc
                    int col_l = ni * 16 + l15;            // d
                    tr[col_l * 72 + row_l] = f2bf(acc[mi][ni][r]);
                }
        int bb = row_base >> 11, n0 = row_base & 2047;
        size_t vbase = ((size_t)(bb * 16 + h) * 32 + (n0 >> 6)) * 4096;
        const int dl = lane >> 3, nc = (lane & 7) * 8;
        for (int i = 0; i < 8; i++) {
            int d = dl + i * 8;
            short8 val = *(const short8*)&tr[d * 72 + nc];
            *(short8*)&Vb[vbase + (size_t)d * 64 + nc] = val;
        }
    }
}

// ---------------------------------------------------------------------------
// Kernel 4: MFMA GEMM (out-proj): C[M][N] = A[M][K] @ Bt[N][K]^T, fp32 out.
// Single-barrier async-dbuf K-loop, 128x128 tile.
// ---------------------------------------------------------------------------
__global__ __launch_bounds__(256) void gemm_out(const ushort* __restrict__ A,
                                                const ushort* __restrict__ Bt,
                                                float* __restrict__ C,
                                                int M, int N, int K) {
    __shared__ ushort As[2][128 * 32];
    __shared__ ushort Bs[2][128 * 32];
    const int tid = threadIdx.x;
    const int wave = tid >> 6, lane = tid & 63;
    const int quad = lane >> 4, l15 = lane & 15;
    const int wm = (wave >> 1) * 64, wn = (wave & 1) * 64;
    const int bm = blockIdx.y * 128, bn = blockIdx.x * 128;

    const int s0 = tid, s1 = tid + 256;
    const int row0 = s0 >> 2, src0 = (s0 & 3) ^ (row0 & 3);
    const int row1 = s1 >> 2, src1 = (s1 & 3) ^ (row1 & 3);

    floatx4 acc[4][4];
    floatx4 z4 = {0.f, 0.f, 0.f, 0.f};
    for (int mi = 0; mi < 4; mi++)
        for (int ni = 0; ni < 4; ni++) acc[mi][ni] = z4;

    const ushort* Ap0 = A + (size_t)(bm + row0) * K + src0 * 8;
    const ushort* Ap1 = A + (size_t)(bm + row1) * K + src1 * 8;
    const ushort* Bp0 = Bt + (size_t)(bn + row0) * K + src0 * 8;
    const ushort* Bp1 = Bt + (size_t)(bn + row1) * K + src1 * 8;

    const int T = K >> 5;
    cp16(Ap0, &As[0][wave * 512]);
    cp16(Ap1, &As[0][2048 + wave * 512]);
    cp16(Bp0, &Bs[0][wave * 512]);
    cp16(Bp1, &Bs[0][2048 + wave * 512]);

    for (int t = 0; t < T; t++) {
        __syncthreads();
        if (t + 1 < T) {
            const int nb = (t + 1) & 1;
            const int k0n = (t + 1) << 5;
            cp16(Ap0 + k0n, &As[nb][wave * 512]);
            cp16(Ap1 + k0n, &As[nb][2048 + wave * 512]);
            cp16(Bp0 + k0n, &Bs[nb][wave * 512]);
            cp16(Bp1 + k0n, &Bs[nb][2048 + wave * 512]);
        }
        const ushort* Ab = As[t & 1];
        const ushort* Bb = Bs[t & 1];
        short8 af[4], bfr[4];
        for (int mi = 0; mi < 4; mi++) {
            int ra = wm + mi * 16 + l15;
            af[mi] = *(const short8*)&Ab[ra * 32 + ((quad ^ (ra & 3)) << 3)];
        }
        for (int ni = 0; ni < 4; ni++) {
            int rb = wn + ni * 16 + l15;
            bfr[ni] = *(const short8*)&Bb[rb * 32 + ((quad ^ (rb & 3)) << 3)];
        }
        for (int mi = 0; mi < 4; mi++)
            for (int ni = 0; ni < 4; ni++)
                acc[mi][ni] = __builtin_amdgcn_mfma_f32_16x16x32_bf16(
                    af[mi], bfr[ni], acc[mi][ni], 0, 0, 0);
    }
    for (int mi = 0; mi < 4; mi++)
        for (int ni = 0; ni < 4; ni++)
            for (int r = 0; r < 4; r++) {
                int row = bm + wm + mi * 16 + quad * 4 + r;
                int col = bn + wn + ni * 16 + l15;
                C[(size_t)row * N + col] = acc[mi][ni][r];
            }
}

// ---------------------------------------------------------------------------
// Kernel 5: causal flash attention (v6 structure, unchanged from R6).
// XCD-local decode: xcd = id&7, bh = xcd*4 + slot/16 -> per-bh K/V pinned to
// one XCD's L2. Single-barrier async-dbuf K/V staging. Fixed-max softmax.
// ---------------------------------------------------------------------------
#define LOG2E8 11.541560327111707f   // 8 * log2(e)

__global__ __launch_bounds__(256) void flash_attn(const ushort* __restrict__ Qt,
                                                  const ushort* __restrict__ Kt,
                                                  const ushort* __restrict__ Vb,
                                                  ushort* __restrict__ O) {
    const int id = blockIdx.x;
    const int xcd = id & 7, slot = id >> 3;
    const int bh = xcd * 4 + (slot >> 4);
    const int pairi = slot & 15;
    const int b = bh >> 4, h = bh & 15;
    const int tid = threadIdx.x;
    const int wave = tid >> 6, lane = tid & 63;
    const int quad = lane >> 4, l15 = lane & 15;

    __shared__ ushort Ks[2][64 * 64];
    __shared__ ushort Vs[2][64 * 64];
    __shared__ ushort Ps[4][16 * 72];

    const int ch0 = tid, ch1 = tid + 256;
    const int r0 = ch0 >> 3, sg0 = (ch0 & 7) ^ (r0 & 7);
    const int r1 = ch1 >> 3, sg1 = (ch1 & 7) ^ (r1 & 7);

    const ushort* Kp0 = Kt + ((size_t)bh * 2048 + r0) * 64 + sg0 * 8;
    const ushort* Kp1 = Kt + ((size_t)bh * 2048 + r1) * 64 + sg1 * 8;
    const ushort* Vp0 = Vb + (size_t)bh * 131072 + r0 * 64 + sg0 * 8;
    const ushort* Vp1 = Vb + (size_t)bh * 131072 + r1 * 64 + sg1 * 8;

    floatx4 z4 = {0.f, 0.f, 0.f, 0.f};

    for (int pass = 0; pass < 2; pass++) {
        const int st = pass ? (31 - pairi) : pairi;
        const int q0 = st * 64;

        const ushort* Qp = Qt + ((size_t)bh * 2048 + q0 + wave * 16 + l15) * 64;
        short8 qf0 = *(const short8*)(Qp + quad * 8);
        short8 qf1 = *(const short8*)(Qp + 32 + quad * 8);

        float rs_acc[4] = {0.f, 0.f, 0.f, 0.f};
        floatx4 o_acc[4];
        for (int ni = 0; ni < 4; ni++) o_acc[ni] = z4;

        __syncthreads();
        cp16(Kp0, &Ks[0][wave * 512]);
        cp16(Kp1, &Ks[0][2048 + wave * 512]);
        cp16(Vp0, &Vs[0][wave * 512]);
        cp16(Vp1, &Vs[0][2048 + wave * 512]);

        for (int kt = 0; kt <= st; kt++) {
            __syncthreads();
            if (kt < st) {
                const int nb2 = (kt + 1) & 1;
                const size_t to = (size_t)(kt + 1) * 4096;
                cp16(Kp0 + to, &Ks[nb2][wave * 512]);
                cp16(Kp1 + to, &Ks[nb2][2048 + wave * 512]);
                cp16(Vp0 + to, &Vs[nb2][wave * 512]);
                cp16(Vp1 + to, &Vs[nb2][2048 + wave * 512]);
            }
            const ushort* Kb = Ks[kt & 1];
            const ushort* Vb_ = Vs[kt & 1];

            floatx4 s_acc[4];
            for (int ni = 0; ni < 4; ni++) s_acc[ni] = z4;
            for (int ni = 0; ni < 4; ni++) {
                int rb = ni * 16 + l15;
                short8 kf0 = *(const short8*)&Kb[rb * 64 + ((quad ^ (rb & 7)) << 3)];
                short8 kf1 = *(const short8*)&Kb[rb * 64 + (((quad + 4) ^ (rb & 7)) << 3)];
                s_acc[ni] = __builtin_amdgcn_mfma_f32_16x16x32_bf16(qf0, kf0, s_acc[ni], 0, 0, 0);
                s_acc[ni] = __builtin_amdgcn_mfma_f32_16x16x32_bf16(qf1, kf1, s_acc[ni], 0, 0, 0);
            }

            const bool diag = (kt == st);
            for (int ni = 0; ni < 4; ni++) {
                const int col_loc = ni * 16 + l15;
                for (int r = 0; r < 4; r++) {
                    float e = __builtin_amdgcn_exp2f(
                        fmaf(s_acc[ni][r], LOG2E8, -LOG2E8));
                    if (diag && col_loc > wave * 16 + quad * 4 + r) e = 0.f;
                    rs_acc[r] += e;
                    Ps[wave][(quad * 4 + r) * 72 + col_loc] = f2bf_rtz(e);
                }
            }

            short8 pa0 = *(const short8*)&Ps[wave][l15 * 72 + quad * 8];
            short8 pa1 = *(const short8*)&Ps[wave][l15 * 72 + 32 + quad * 8];
            for (int ni = 0; ni < 4; ni++) {
                int rv = ni * 16 + l15;
                short8 v0 = *(const short8*)&Vb_[rv * 64 + ((quad ^ (rv & 7)) << 3)];
                short8 v1 = *(const short8*)&Vb_[rv * 64 + (((quad + 4) ^ (rv & 7)) << 3)];
                o_acc[ni] = __builtin_amdgcn_mfma_f32_16x16x32_bf16(pa0, v0, o_acc[ni], 0, 0, 0);
                o_acc[ni] = __builtin_amdgcn_mfma_f32_16x16x32_bf16(pa1, v1, o_acc[ni], 0, 0, 0);
            }
        }

        for (int r = 0; r < 4; r++) {
            float rs = rs_acc[r];
            for (int off = 1; off < 16; off <<= 1) rs += __shfl_xor(rs, off);
            float inv = 1.0f / rs;
            int grow = q0 + wave * 16 + quad * 4 + r;
            size_t rowbase = ((size_t)b * 2048 + grow) * 1024 + h * 64;
            for (int ni = 0; ni < 4; ni++)
                O[rowbase + ni * 16 + l15] = f2bf(o_acc[ni][r] * inv);
        }
    }
}

// ---------------------------------------------------------------------------
extern "C" void kernel_launch(void* const* d_in, const int* in_sizes, int n_in,
                              void* d_out, int out_size, void* d_ws, size_t ws_size,
                              hipStream_t stream) {
    const float* x = (const float*)d_in[0];
    const float* ln_w = (const float*)d_in[1];
    const float* ln_b = (const float*)d_in[2];
    const float* W_qkv = (const float*)d_in[3];
    const float* W_out = (const float*)d_in[4];

    char* w = (char*)d_ws;
    ushort* xn    = (ushort*)(w);                          // 8 MiB
    ushort* WqkvT = (ushort*)(w + (8ull << 20));           // 6 MiB
    ushort* WoutT = (ushort*)(w + (14ull << 20));          // 2 MiB
    ushort* Vb    = (ushort*)(w + (16ull << 20));          // 8 MiB
    ushort* Qt    = (ushort*)(w + (24ull << 20));          // 8 MiB
    ushort* Kt    = (ushort*)(w + (32ull << 20));          // 8 MiB
    ushort* obuf  = (ushort*)(w + (40ull << 20));          // 8 MiB -> 48 MiB total

    transpose_cast2<<<dim3(128, 32), dim3(32, 8), 0, stream>>>(W_qkv, W_out, WqkvT, WoutT);
    ln_kernel<<<4096, 256, 0, stream>>>(x, ln_w, ln_b, xn);
    gemm_qkv_fused<<<dim3(24, 32), 256, 0, stream>>>(xn, WqkvT, Qt, Kt, Vb);
    flash_attn<<<512, 256, 0, stream>>>(Qt, Kt, Vb, obuf);
    gemm_out<<<dim3(8, 32), 256, 0, stream>>>(obuf, WoutT, (float*)d_out, 4096, 1024, 1024);
}